// Round 12
// baseline (487.639 us; speedup 1.0000x reference)
//
#include <hip/hip_runtime.h>
#include <math.h>

#define NEGF -1000000000.0f
#define EPSF 1e-7f

// B=32, T=256, IN=64, H=128, 4H=512, TOP_K=5

// Raw barrier: LDS-only drain + s_barrier (keeps global prefetch in flight).
#define RAWBAR() asm volatile("s_waitcnt lgkmcnt(0)\n\ts_barrier" ::: "memory")

__device__ __forceinline__ float fsigmoid(float x) {
  return 1.0f / (1.0f + __expf(-x));               // overflow -> correct limit
}
__device__ __forceinline__ float ftanh(float x) {
  return 1.0f - 2.0f / (1.0f + __expf(2.0f * x));  // limits +-1: correct
}

// wave64 all-reduce sum via DPP (row_shr 1/2/4/8 + row_bcast 15/31), ~35 cyc.
__device__ __forceinline__ float wave_allsum(float v) {
#if __has_builtin(__builtin_amdgcn_update_dpp) && __has_builtin(__builtin_amdgcn_readlane)
  float f = v;
#define DPPSTEP(ctrl, rmask) { \
    int t = __builtin_amdgcn_update_dpp(0, __builtin_bit_cast(int, f), \
                                        ctrl, rmask, 0xf, true); \
    f += __builtin_bit_cast(float, t); }
  DPPSTEP(0x111, 0xf)   // row_shr:1
  DPPSTEP(0x112, 0xf)   // row_shr:2
  DPPSTEP(0x114, 0xf)   // row_shr:4
  DPPSTEP(0x118, 0xf)   // row_shr:8  -> lane15 of each row has row sum
  DPPSTEP(0x142, 0xa)   // row_bcast:15 into rows 1,3
  DPPSTEP(0x143, 0x8)   // row_bcast:31 into row 3 -> lane 63 = total
#undef DPPSTEP
  return __builtin_bit_cast(float,
      __builtin_amdgcn_readlane(__builtin_bit_cast(int, f), 63));
#else
  for (int off = 1; off < 64; off <<= 1) v += __shfl_xor(v, off, 64);
  return v;
#endif
}

// SINGLE fused kernel: full recurrence + in-Phase-A x.W_ih, one block per
// batch element, 512 threads (8 waves, 2/SIMD, 256-VGPR cap).
//
// WHY FUSED: the two-kernel split carried an invariant ~83us of non-lstm
// time across FIVE different xw_kernel implementations (compute floor ~5us)
// while the single-kernel R2 run showed only ~13us of non-kernel overhead
// -> the cost is dispatch overhead, not xw code. The gate preactivation is
// one concatenated dot [W_ih|W_hh].[x;h]: thread (q=tid>>7, p=tid&127)
// owns 4 gates (p, p+128, p+256, p+384) with W_hh K-chunk q (32 floats) AND
// W_ih K-chunk q (16 floats) = 192 resident weight floats (<256 cap; R11
// measured VGPR=108 with 128). x rows live in an 8-row LDS ring filled 5
// steps ahead by wave 7 in its idle S1->S2 window — never on the critical
// path. sh_part/GSUM/Phase B/delta-cancellation byte-identical to R11.
// Tripwire: WRITE_SIZE must stay ~KBs (MBs = spill, path dead).
//
// DELTA CANCELLATION (unchanged):
//   s[t] = a + d[t]; delta = a + top5(d)[4] + EPS  =>  w[t] = d[t]-t5v4-EPS
//   independent of a. Sparse attention = 4 register-indexed LDS row gathers
//   whose addresses are known from the PREVIOUS step (prefetched before S1).
//   Raw-score path (rem<=5) kept as a 5-step special case.
__global__
__attribute__((amdgpu_flat_work_group_size(512, 512), amdgpu_waves_per_eu(2, 2)))
void lstm_attn(
    const float* __restrict__ x, const float* __restrict__ W_ih,
    const float* __restrict__ W_hh, const float* __restrict__ b_ih,
    const float* __restrict__ b_hh, const float* __restrict__ w_t,
    float* __restrict__ out)
{
  const int b   = blockIdx.x;
  const int tid = threadIdx.x;
  const int l   = tid & 63;       // lane
  const int wid = tid >> 6;
  const int p   = tid & 127;      // element id (gate base)
  const int q   = tid >> 7;       // K-chunk 0..3 (wave-uniform)

  __shared__ float ho[257 * 128];     // fp32 h history (131584 B)
  __shared__ float sh_part[4 * 512];  // gate partials [q][gate] (8 KB)
  __shared__ float sxr[8][64];        // x-row ring (2 KB), row t at slot t&7
  __shared__ float sh_d[8];           // d[t] cache, only needed for t<5

  // one-time weight load: W_hh 4 rows x 8 float4 + W_ih 4 rows x 4 float4
  const float4* pI = (const float4*)(W_hh + (size_t)(p      ) * 128 + (q << 5));
  const float4* pF = (const float4*)(W_hh + (size_t)(p + 128) * 128 + (q << 5));
  const float4* pG = (const float4*)(W_hh + (size_t)(p + 256) * 128 + (q << 5));
  const float4* pO = (const float4*)(W_hh + (size_t)(p + 384) * 128 + (q << 5));
  float4 wI0 = pI[0], wI1 = pI[1], wI2 = pI[2], wI3 = pI[3],
         wI4 = pI[4], wI5 = pI[5], wI6 = pI[6], wI7 = pI[7];
  float4 wF0 = pF[0], wF1 = pF[1], wF2 = pF[2], wF3 = pF[3],
         wF4 = pF[4], wF5 = pF[5], wF6 = pF[6], wF7 = pF[7];
  float4 wG0 = pG[0], wG1 = pG[1], wG2 = pG[2], wG3 = pG[3],
         wG4 = pG[4], wG5 = pG[5], wG6 = pG[6], wG7 = pG[7];
  float4 wO0 = pO[0], wO1 = pO[1], wO2 = pO[2], wO3 = pO[3],
         wO4 = pO[4], wO5 = pO[5], wO6 = pO[6], wO7 = pO[7];
  const float4* xI = (const float4*)(W_ih + (size_t)(p      ) * 64 + (q << 4));
  const float4* xF = (const float4*)(W_ih + (size_t)(p + 128) * 64 + (q << 4));
  const float4* xG = (const float4*)(W_ih + (size_t)(p + 256) * 64 + (q << 4));
  const float4* xO = (const float4*)(W_ih + (size_t)(p + 384) * 64 + (q << 4));
  float4 vI0 = xI[0], vI1 = xI[1], vI2 = xI[2], vI3 = xI[3];
  float4 vF0 = xF[0], vF1 = xF[1], vF2 = xF[2], vF3 = xF[3];
  float4 vG0 = xG[0], vG1 = xG[1], vG2 = xG[2], vG3 = xG[3];
  float4 vO0 = xO[0], vO1 = xO[1], vO2 = xO[2], vO3 = xO[3];
  const float biasI = (q == 0) ? b_ih[p      ] + b_hh[p      ] : 0.0f;
  const float biasF = (q == 0) ? b_ih[p + 128] + b_hh[p + 128] : 0.0f;
  const float biasG = (q == 0) ? b_ih[p + 256] + b_hh[p + 256] : 0.0f;
  const float biasO = (q == 0) ? b_ih[p + 384] + b_hh[p + 384] : 0.0f;

  const float* xg = x + (size_t)b * 256 * 64;

  // wave0 per-lane persistent state (h elements j0=2l, j1=2l+1)
  const int j0 = 2 * l, j1 = 2 * l + 1;
  float c0 = 0.0f, c1 = 0.0f;
  float wa0 = 0.0f, wa1 = 0.0f, wb0 = 0.0f, wb1 = 0.0f;
  float t5v0 = 0.0f, t5v1 = NEGF, t5v2 = NEGF, t5v3 = NEGF, t5v4 = NEGF;
  int   t5i0 = 0, t5i1 = 0, t5i2 = 0, t5i3 = 0;
  float gn0 = 0.0f, gn1 = 0.0f, gn2 = 0.0f, gn3 = 0.0f;
  int   ofs0 = 0, ofs1 = 0, ofs2 = 0, ofs3 = 0;

  if (wid == 0) {
    wa0 = w_t[j0];       wa1 = w_t[j1];
    wb0 = w_t[128 + j0]; wb1 = w_t[128 + j1];
    *(float2*)(ho + j0) = make_float2(0.0f, 0.0f);   // h(-1) = 0 (row 0)
    __builtin_amdgcn_s_setprio(1);   // wave0 is always the barrier straggler
  }
  if (wid == 7) {                     // prologue: stage x rows 0..4
    sxr[0][l] = xg[l];
    sxr[1][l] = xg[64 + l];
    sxr[2][l] = xg[128 + l];
    sxr[3][l] = xg[192 + l];
    sxr[4][l] = xg[256 + l];
  }
  if (tid == 0) sh_d[0] = 0.0f;
  __syncthreads();   // one-time full sync

  for (int i = 0; i < 256; ++i) {
    const int rem = i + 1;
    float hn0 = 0.0f, hn1 = 0.0f;

    // wave7: issue x row i+5 load early (written after S1, hidden latency)
    float xnv = 0.0f;
    if (wid == 7 && i < 251) xnv = xg[(size_t)(i + 5) * 64 + l];

    // ---- Phase A: 4 gate-partials = bias + W_ih.x-chunk + W_hh.h-chunk ----
    float aI = biasI, aF = biasF, aG = biasG, aO = biasO;
    const float4* xx4 = (const float4*)(&sxr[i & 7][q << 4]);
#define XS(k) { float4 xv = xx4[k]; \
    aI = fmaf(vI##k.x, xv.x, aI); aI = fmaf(vI##k.y, xv.y, aI); \
    aI = fmaf(vI##k.z, xv.z, aI); aI = fmaf(vI##k.w, xv.w, aI); \
    aF = fmaf(vF##k.x, xv.x, aF); aF = fmaf(vF##k.y, xv.y, aF); \
    aF = fmaf(vF##k.z, xv.z, aF); aF = fmaf(vF##k.w, xv.w, aF); \
    aG = fmaf(vG##k.x, xv.x, aG); aG = fmaf(vG##k.y, xv.y, aG); \
    aG = fmaf(vG##k.z, xv.z, aG); aG = fmaf(vG##k.w, xv.w, aG); \
    aO = fmaf(vO##k.x, xv.x, aO); aO = fmaf(vO##k.y, xv.y, aO); \
    aO = fmaf(vO##k.z, xv.z, aO); aO = fmaf(vO##k.w, xv.w, aO); }
    XS(0) XS(1) XS(2) XS(3)
#undef XS
    const float4* hh4 = (const float4*)(ho + i * 128 + (q << 5));
#define KS(k) { float4 hv = hh4[k]; \
    aI = fmaf(wI##k.x, hv.x, aI); aI = fmaf(wI##k.y, hv.y, aI); \
    aI = fmaf(wI##k.z, hv.z, aI); aI = fmaf(wI##k.w, hv.w, aI); \
    aF = fmaf(wF##k.x, hv.x, aF); aF = fmaf(wF##k.y, hv.y, aF); \
    aF = fmaf(wF##k.z, hv.z, aF); aF = fmaf(wF##k.w, hv.w, aF); \
    aG = fmaf(wG##k.x, hv.x, aG); aG = fmaf(wG##k.y, hv.y, aG); \
    aG = fmaf(wG##k.z, hv.z, aG); aG = fmaf(wG##k.w, hv.w, aG); \
    aO = fmaf(wO##k.x, hv.x, aO); aO = fmaf(wO##k.y, hv.y, aO); \
    aO = fmaf(wO##k.z, hv.z, aO); aO = fmaf(wO##k.w, hv.w, aO); }
    KS(0) KS(1) KS(2) KS(3) KS(4) KS(5) KS(6) KS(7)
#undef KS
    {
      float* sp = sh_part + (q << 9) + p;
      sp[0]   = aI;
      sp[128] = aF;
      sp[256] = aG;
      sp[384] = aO;
    }

    // gather prefetch: addresses known from previous step's top-5; ho rows
    // are append-only so reading before the barrier is race-free.
    float2 hv0, hv1, hv2, hv3;
    if (wid == 0 && i >= 5) {
      hv0 = *(const float2*)(ho + ofs0);
      hv1 = *(const float2*)(ho + ofs1);
      hv2 = *(const float2*)(ho + ofs2);
      hv3 = *(const float2*)(ho + ofs3);
    }
    RAWBAR();                                             // S1

    if (wid == 0) {
      // ---- Phase B: LSTM cell (2 elements/lane) ----
#define GSUM(base) ({ \
      float2 x0 = ((const float2*)(sh_part        + (base)))[l]; \
      float2 x1 = ((const float2*)(sh_part +  512 + (base)))[l]; \
      float2 x2 = ((const float2*)(sh_part + 1024 + (base)))[l]; \
      float2 x3 = ((const float2*)(sh_part + 1536 + (base)))[l]; \
      float2 r; r.x = (x0.x + x1.x) + (x2.x + x3.x); \
      r.y = (x0.y + x1.y) + (x2.y + x3.y); r; })
      float2 Pi = GSUM(0), Pf = GSUM(128), Pg = GSUM(256), Po = GSUM(384);
#undef GSUM
      c0 = fsigmoid(Pf.x) * c0 + fsigmoid(Pi.x) * ftanh(Pg.x);
      c1 = fsigmoid(Pf.y) * c1 + fsigmoid(Pi.y) * ftanh(Pg.y);
      float hc0 = fsigmoid(Po.x) * ftanh(c0);
      float hc1 = fsigmoid(Po.y) * ftanh(c1);

      float at0, at1;
      if (i >= 5) {
        // ---- sparse attention: 4 pre-fetched rows, register weights ----
        at0 = gn0 * hv0.x;            at1 = gn0 * hv0.y;
        at0 = fmaf(gn1, hv1.x, at0);  at1 = fmaf(gn1, hv1.y, at1);
        at0 = fmaf(gn2, hv2.x, at0);  at1 = fmaf(gn2, hv2.y, at1);
        at0 = fmaf(gn3, hv3.x, at0);  at1 = fmaf(gn3, hv3.y, at1);
      } else {
        // ---- rem<=5: attn weights are RAW scores s = a + d[t], no norm ----
        float a = wave_allsum(ftanh(hc0) * wa0 + ftanh(hc1) * wa1);
        at0 = 0.0f; at1 = 0.0f;
        for (int t = 0; t <= i; ++t) {
          float s = a + sh_d[t];
          float2 hv = *(const float2*)(ho + t * 128 + j0);
          at0 = fmaf(s, hv.x, at0);
          at1 = fmaf(s, hv.y, at1);
        }
      }
      hn0 = hc0 + at0; hn1 = hc1 + at1;
      *(float2*)(ho + rem * 128 + j0) = make_float2(hn0, hn1);
      if (i == 255) {
        out[b * 128 + j0] = at0; out[b * 128 + j1] = at1;   // attn_c
        // attn_w: zero except at the <=4 above-threshold top-5 indices
        #pragma unroll
        for (int m = 0; m < 4; ++m) {
          int t = l + 64 * m;
          float val = 0.0f;
          if (t == t5i0) val = gn0;
          if (t == t5i1) val = gn1;
          if (t == t5i2) val = gn2;
          if (t == t5i3) val = gn3;
          out[4096 + b * 256 + t] = val;
        }
      }
    } else if (wid == 7 && i < 251) {
      sxr[(i + 5) & 7][l] = xnv;      // idle window: publish x row i+5
    }
    RAWBAR();                                             // S2

    // ---- tail (off critical path: overlaps other waves' next Phase A) ----
    if (wid == 0 && i < 255) {
      float dn = wave_allsum(ftanh(hn0) * wb0 + ftanh(hn1) * wb1);
      if (l == 0 && i < 4) sh_d[rem] = dn;   // only raw-score steps read it
      // replicated top-5 (value,index) insert — identical in every lane
      float v = dn; int vi = rem;
      if (v > t5v0) { float tv = t5v0; int ti = t5i0; t5v0 = v; t5i0 = vi; v = tv; vi = ti; }
      if (v > t5v1) { float tv = t5v1; int ti = t5i1; t5v1 = v; t5i1 = vi; v = tv; vi = ti; }
      if (v > t5v2) { float tv = t5v2; int ti = t5i2; t5v2 = v; t5i2 = vi; v = tv; vi = ti; }
      if (v > t5v3) { float tv = t5v3; int ti = t5i3; t5v3 = v; t5i3 = vi; v = tv; vi = ti; }
      if (v > t5v4) { t5v4 = v; }
      // next step's normalized gather weights + offsets (delta cancellation:
      // w[t] = d[t] - t5v4 - EPS, nonzero only among top-4)
      float g0 = fmaxf(t5v0 - t5v4 - EPSF, 0.0f);
      float g1 = fmaxf(t5v1 - t5v4 - EPSF, 0.0f);
      float g2 = fmaxf(t5v2 - t5v4 - EPSF, 0.0f);
      float g3 = fmaxf(t5v3 - t5v4 - EPSF, 0.0f);
      float inv = 1.0f / (((g0 + g1) + (g2 + g3)) + EPSF);
      gn0 = g0 * inv; gn1 = g1 * inv; gn2 = g2 * inv; gn3 = g3 * inv;
      ofs0 = (t5i0 << 7) + j0; ofs1 = (t5i1 << 7) + j0;
      ofs2 = (t5i2 << 7) + j0; ofs3 = (t5i3 << 7) + j0;
    }
  }
}

extern "C" void kernel_launch(void* const* d_in, const int* in_sizes, int n_in,
                              void* d_out, int out_size, void* d_ws, size_t ws_size,
                              hipStream_t stream) {
  const float* x    = (const float*)d_in[0];  // (32,256,64)
  const float* W_ih = (const float*)d_in[1];  // (512,64)
  const float* W_hh = (const float*)d_in[2];  // (512,128)
  const float* b_ih = (const float*)d_in[3];  // (512,)
  const float* b_hh = (const float*)d_in[4];  // (512,)
  const float* w_t  = (const float*)d_in[5];  // (256,1)
  float* out = (float*)d_out;                 // [0:4096) attn_c, [4096:12288) attn_w

  (void)d_ws; (void)ws_size;                  // workspace no longer needed
  lstm_attn<<<dim3(32), 512, 0, stream>>>(x, W_ih, W_hh, b_ih, b_hh, w_t, out);
}

// Round 13
// 367.510 us; speedup vs baseline: 1.3269x; 1.3269x over previous
//
#include <hip/hip_runtime.h>
#include <math.h>

#define NEGF -1000000000.0f
#define EPSF 1e-7f

// B=32, T=256, IN=64, H=128, 4H=512, TOP_K=5

typedef float v4f __attribute__((ext_vector_type(4)));
#define FMA4(a, b, c) __builtin_elementwise_fma((a), (b), (c))

// Raw barrier: LDS-only drain + s_barrier (keeps global prefetch in flight).
#define RAWBAR() asm volatile("s_waitcnt lgkmcnt(0)\n\ts_barrier" ::: "memory")

__device__ __forceinline__ float fsigmoid(float x) {
  return 1.0f / (1.0f + __expf(-x));               // overflow -> correct limit
}
__device__ __forceinline__ float ftanh(float x) {
  return 1.0f - 2.0f / (1.0f + __expf(2.0f * x));  // limits +-1: correct
}

// wave64 all-reduce sum via DPP (row_shr 1/2/4/8 + row_bcast 15/31), ~35 cyc.
__device__ __forceinline__ float wave_allsum(float v) {
#if __has_builtin(__builtin_amdgcn_update_dpp) && __has_builtin(__builtin_amdgcn_readlane)
  float f = v;
#define DPPSTEP(ctrl, rmask) { \
    int t = __builtin_amdgcn_update_dpp(0, __builtin_bit_cast(int, f), \
                                        ctrl, rmask, 0xf, true); \
    f += __builtin_bit_cast(float, t); }
  DPPSTEP(0x111, 0xf)   // row_shr:1
  DPPSTEP(0x112, 0xf)   // row_shr:2
  DPPSTEP(0x114, 0xf)   // row_shr:4
  DPPSTEP(0x118, 0xf)   // row_shr:8  -> lane15 of each row has row sum
  DPPSTEP(0x142, 0xa)   // row_bcast:15 into rows 1,3
  DPPSTEP(0x143, 0x8)   // row_bcast:31 into row 3 -> lane 63 = total
#undef DPPSTEP
  return __builtin_bit_cast(float,
      __builtin_amdgcn_readlane(__builtin_bit_cast(int, f), 63));
#else
  for (int off = 1; off < 64; off <<= 1) v += __shfl_xor(v, off, 64);
  return v;
#endif
}

// Kernel 1: xw[b][t][g] = x[b][t] . W_ih[g] + (b_ih[g]+b_hh[g])
// EXACT round-3 version (proven).
__global__ __launch_bounds__(512) void xw_kernel(
    const float* __restrict__ x, const float* __restrict__ W_ih,
    const float* __restrict__ b_ih, const float* __restrict__ b_hh,
    float* __restrict__ xw)
{
  const int t0 = blockIdx.x * 32;
  const int b  = blockIdx.y;
  const int g  = threadIdx.x;

  __shared__ float sx[32 * 64];              // 8 KB
  ((float4*)sx)[threadIdx.x] =
      ((const float4*)(x + (size_t)(b * 256 + t0) * 64))[threadIdx.x];

  const float4* wr = (const float4*)(W_ih + (size_t)g * 64);
  float4 w0 = wr[0],  w1 = wr[1],  w2 = wr[2],  w3 = wr[3],
         w4 = wr[4],  w5 = wr[5],  w6 = wr[6],  w7 = wr[7],
         w8 = wr[8],  w9 = wr[9],  w10 = wr[10], w11 = wr[11],
         w12 = wr[12], w13 = wr[13], w14 = wr[14], w15 = wr[15];
  const float bias = b_ih[g] + b_hh[g];
  __syncthreads();

  float* dst = xw + (size_t)(b * 256 + t0) * 512 + g;
  for (int tt = 0; tt < 32; ++tt) {
    const float4* xr = (const float4*)(sx + tt * 64);
    float a0 = 0.0f, a1 = 0.0f, a2 = 0.0f, a3 = 0.0f;
#define XSTEP(j) { float4 hv = xr[j]; \
    a0 = fmaf(w##j.x, hv.x, a0); a1 = fmaf(w##j.y, hv.y, a1); \
    a2 = fmaf(w##j.z, hv.z, a2); a3 = fmaf(w##j.w, hv.w, a3); }
    XSTEP(0) XSTEP(1) XSTEP(2) XSTEP(3) XSTEP(4) XSTEP(5) XSTEP(6) XSTEP(7)
    XSTEP(8) XSTEP(9) XSTEP(10) XSTEP(11) XSTEP(12) XSTEP(13) XSTEP(14) XSTEP(15)
#undef XSTEP
    dst[(size_t)tt * 512] = (a0 + a1) + (a2 + a3) + bias;
  }
}

// Kernel 2: full recurrence, one block per batch, 512 threads (8 waves,
// 2/SIMD). R11 base (314.6us) + two register-neutral cuts:
//  1. Phase A in packed fp32 (v_pk_fma_f32 via elementwise fma on v4f):
//     128 scalar FMA -> 32 pk ops/thread (issue 512 -> ~256 cyc/SIMD/step).
//  2. Phase B split across waves 0+1 (1 element/lane, j=(wid<<6)+l):
//     per-wave transcendental issue halves, chains run on 2 SIMDs.
//     Cross-wave dn exchanged via sh_dn[2] written pre-S2, combined tail
//     replicated in both waves post-S2. i<5 raw path: one extra all-wave
//     barrier (5 steps only).
// Fusion of W_ih is permanently dead: R12 showed +16 float4 tips the
// 2-wave/SIMD unified-file budget into spill (VGPR pinned 128, WRITE 544K).
//
// DELTA CANCELLATION (unchanged):
//   s[t] = a + d[t]; delta = a + top5(d)[4] + EPS  =>  w[t] = d[t]-t5v4-EPS
//   independent of a. Sparse attention = 4 register-indexed LDS gathers,
//   addresses known from the PREVIOUS step (prefetched before S1).
__global__
__attribute__((amdgpu_flat_work_group_size(512, 512), amdgpu_waves_per_eu(2, 2)))
void lstm_attn(
    const float* __restrict__ xw, const float* __restrict__ W_hh,
    const float* __restrict__ w_t, float* __restrict__ out)
{
  const int b   = blockIdx.x;
  const int tid = threadIdx.x;
  const int l   = tid & 63;       // lane
  const int wid = tid >> 6;
  const int p   = tid & 127;      // element id (gate base)
  const int q   = tid >> 7;       // K-chunk 0..3 (wave-uniform)

  __shared__ float ho[257 * 128];     // fp32 h history (131584 B)
  __shared__ float sh_part[4 * 512];  // gate partials [q][gate] (8 KB)
  __shared__ float sh_d[8];           // d[t] cache (raw-score steps)
  __shared__ float sh_pa[2];          // partial a (i<5 path)
  __shared__ float sh_dn[2];          // partial dn (every step)

  // one-time weight load: 4 gate rows x 8 v4f = 32 named v4f
  const v4f* pI = (const v4f*)(W_hh + (size_t)(p      ) * 128 + (q << 5));
  const v4f* pF = (const v4f*)(W_hh + (size_t)(p + 128) * 128 + (q << 5));
  const v4f* pG = (const v4f*)(W_hh + (size_t)(p + 256) * 128 + (q << 5));
  const v4f* pO = (const v4f*)(W_hh + (size_t)(p + 384) * 128 + (q << 5));
  v4f wI0 = pI[0], wI1 = pI[1], wI2 = pI[2], wI3 = pI[3],
      wI4 = pI[4], wI5 = pI[5], wI6 = pI[6], wI7 = pI[7];
  v4f wF0 = pF[0], wF1 = pF[1], wF2 = pF[2], wF3 = pF[3],
      wF4 = pF[4], wF5 = pF[5], wF6 = pF[6], wF7 = pF[7];
  v4f wG0 = pG[0], wG1 = pG[1], wG2 = pG[2], wG3 = pG[3],
      wG4 = pG[4], wG5 = pG[5], wG6 = pG[6], wG7 = pG[7];
  v4f wO0 = pO[0], wO1 = pO[1], wO2 = pO[2], wO3 = pO[3],
      wO4 = pO[4], wO5 = pO[5], wO6 = pO[6], wO7 = pO[7];

  // waves 0,1 per-lane persistent state: element j
  const int j = (wid << 6) + l;
  float cc = 0.0f;
  float wa = 0.0f, wb = 0.0f;
  float t5v0 = 0.0f, t5v1 = NEGF, t5v2 = NEGF, t5v3 = NEGF, t5v4 = NEGF;
  int   t5i0 = 0, t5i1 = 0, t5i2 = 0, t5i3 = 0;
  float gn0 = 0.0f, gn1 = 0.0f, gn2 = 0.0f, gn3 = 0.0f;
  int   ofs0 = 0, ofs1 = 0, ofs2 = 0, ofs3 = 0;

  if (wid < 2) {
    wa = w_t[j]; wb = w_t[128 + j];
    ho[j] = 0.0f;                      // h(-1) = 0 (row 0)
    __builtin_amdgcn_s_setprio(1);     // cell waves are barrier stragglers
  }
  if (tid == 0) sh_d[0] = 0.0f;
  __syncthreads();   // one-time full sync

  const float* xwb = xw + (size_t)b * 256 * 512;
  float xcI = 0.0f, xcF = 0.0f, xcG = 0.0f, xcO = 0.0f;
  if (q == 0) {
    xcI = xwb[p];       xcF = xwb[p + 128];
    xcG = xwb[p + 256]; xcO = xwb[p + 384];
  }

  for (int i = 0; i < 256; ++i) {
    const int rem = i + 1;

    // ---- Phase A: 4 gate-partials, packed fp32 (32 pk-FMA/thread) ----
    v4f aI = {xcI, 0.0f, 0.0f, 0.0f};
    v4f aF = {xcF, 0.0f, 0.0f, 0.0f};
    v4f aG = {xcG, 0.0f, 0.0f, 0.0f};
    v4f aO = {xcO, 0.0f, 0.0f, 0.0f};
    if (q == 0 && i < 255) {          // prefetch next step's xw (stays in
      const float* xn = xwb + (size_t)(i + 1) * 512;     // flight over bars)
      xcI = xn[p];       xcF = xn[p + 128];
      xcG = xn[p + 256]; xcO = xn[p + 384];
    }
    const v4f* hh4 = (const v4f*)(ho + i * 128 + (q << 5));
#define KS(k) { v4f hv = hh4[k]; \
    aI = FMA4(wI##k, hv, aI); aF = FMA4(wF##k, hv, aF); \
    aG = FMA4(wG##k, hv, aG); aO = FMA4(wO##k, hv, aO); }
    KS(0) KS(1) KS(2) KS(3) KS(4) KS(5) KS(6) KS(7)
#undef KS
    {
      float* sp = sh_part + (q << 9) + p;
      sp[0]   = (aI.x + aI.y) + (aI.z + aI.w);
      sp[128] = (aF.x + aF.y) + (aF.z + aF.w);
      sp[256] = (aG.x + aG.y) + (aG.z + aG.w);
      sp[384] = (aO.x + aO.y) + (aO.z + aO.w);
    }

    // gather prefetch: addresses known from previous step's top-5; ho rows
    // are append-only so reading before the barrier is race-free.
    float hv0 = 0.0f, hv1 = 0.0f, hv2 = 0.0f, hv3 = 0.0f;
    if (wid < 2 && i >= 5) {
      hv0 = ho[ofs0]; hv1 = ho[ofs1]; hv2 = ho[ofs2]; hv3 = ho[ofs3];
    }
    RAWBAR();                                             // S1

    // ---- Phase B: LSTM cell, split across waves 0 and 1 (1 elem/lane) ----
    float hc = 0.0f, at = 0.0f;
    if (wid < 2) {
      const float* s0 = sh_part + j;
      float Pi = (s0[0]         + s0[512])         + (s0[1024]         + s0[1536]);
      float Pf = (s0[128]       + s0[640])         + (s0[1152]         + s0[1664]);
      float Pg = (s0[256]       + s0[768])         + (s0[1280]         + s0[1792]);
      float Po = (s0[384]       + s0[896])         + (s0[1408]         + s0[1920]);
      cc = fsigmoid(Pf) * cc + fsigmoid(Pi) * ftanh(Pg);
      hc = fsigmoid(Po) * ftanh(cc);
    }
    if (i < 5) {
      // raw-score path: needs block-wide a = sum over all 128 elements
      if (wid < 2) {
        float pa = wave_allsum(ftanh(hc) * wa);
        if (l == 0) sh_pa[wid] = pa;
      }
      RAWBAR();                       // extra all-wave barrier (5 steps only)
      if (wid < 2) {
        float a = sh_pa[0] + sh_pa[1];
        at = 0.0f;
        for (int t = 0; t <= i; ++t)
          at = fmaf(a + sh_d[t], ho[t * 128 + j], at);
      }
    } else if (wid < 2) {
      at = gn0 * hv0;
      at = fmaf(gn1, hv1, at);
      at = fmaf(gn2, hv2, at);
      at = fmaf(gn3, hv3, at);
    }
    if (wid < 2) {
      float hn = hc + at;
      ho[rem * 128 + j] = hn;
      float pdn = wave_allsum(ftanh(hn) * wb);   // pre-S2 partial
      if (l == 0) sh_dn[wid] = pdn;
      if (i == 255) {
        out[b * 128 + j] = at;                   // attn_c
        if (wid == 0) {
          // attn_w: zero except at the <=4 above-threshold top-5 indices
          #pragma unroll
          for (int m = 0; m < 4; ++m) {
            int t = l + 64 * m;
            float val = 0.0f;
            if (t == t5i0) val = gn0;
            if (t == t5i1) val = gn1;
            if (t == t5i2) val = gn2;
            if (t == t5i3) val = gn3;
            out[4096 + b * 256 + t] = val;
          }
        }
      }
    }
    RAWBAR();                                             // S2

    // ---- tail (replicated in waves 0+1, off critical path) ----
    if (wid < 2 && i < 255) {
      float dn = sh_dn[0] + sh_dn[1];
      if (wid == 0 && l == 0 && i < 4) sh_d[rem] = dn;
      // replicated top-5 (value,index) insert — identical in both waves
      float v = dn; int vi = rem;
      if (v > t5v0) { float tv = t5v0; int ti = t5i0; t5v0 = v; t5i0 = vi; v = tv; vi = ti; }
      if (v > t5v1) { float tv = t5v1; int ti = t5i1; t5v1 = v; t5i1 = vi; v = tv; vi = ti; }
      if (v > t5v2) { float tv = t5v2; int ti = t5i2; t5v2 = v; t5i2 = vi; v = tv; vi = ti; }
      if (v > t5v3) { float tv = t5v3; int ti = t5i3; t5v3 = v; t5i3 = vi; v = tv; vi = ti; }
      if (v > t5v4) { t5v4 = v; }
      // next step's normalized gather weights + offsets (delta cancellation)
      float g0 = fmaxf(t5v0 - t5v4 - EPSF, 0.0f);
      float g1 = fmaxf(t5v1 - t5v4 - EPSF, 0.0f);
      float g2 = fmaxf(t5v2 - t5v4 - EPSF, 0.0f);
      float g3 = fmaxf(t5v3 - t5v4 - EPSF, 0.0f);
      float inv = 1.0f / (((g0 + g1) + (g2 + g3)) + EPSF);
      gn0 = g0 * inv; gn1 = g1 * inv; gn2 = g2 * inv; gn3 = g3 * inv;
      ofs0 = (t5i0 << 7) + j; ofs1 = (t5i1 << 7) + j;
      ofs2 = (t5i2 << 7) + j; ofs3 = (t5i3 << 7) + j;
    }
  }
}

extern "C" void kernel_launch(void* const* d_in, const int* in_sizes, int n_in,
                              void* d_out, int out_size, void* d_ws, size_t ws_size,
                              hipStream_t stream) {
  const float* x    = (const float*)d_in[0];  // (32,256,64)
  const float* W_ih = (const float*)d_in[1];  // (512,64)
  const float* W_hh = (const float*)d_in[2];  // (512,128)
  const float* b_ih = (const float*)d_in[3];  // (512,)
  const float* b_hh = (const float*)d_in[4];  // (512,)
  const float* w_t  = (const float*)d_in[5];  // (256,1)
  float* out = (float*)d_out;                 // [0:4096) attn_c, [4096:12288) attn_w

  float* xw = (float*)d_ws;                   // 32*256*512 fp32 = 16 MB

  xw_kernel<<<dim3(8, 32), 512, 0, stream>>>(x, W_ih, b_ih, b_hh, xw);
  lstm_attn<<<dim3(32), 512, 0, stream>>>(xw, W_hh, w_t, out);
}